// Round 1
// baseline (105.162 us; speedup 1.0000x reference)
//
#include <hip/hip_runtime.h>
#include <math.h>

// LipschitzNorm: E=800000 edges, N=50000 nodes, H=4 heads, D=32 dims (fp32).
// out[e,h] = alpha[e,h] / (natt[h] * sqrt(g[e] + ||x[e,h]||^2) + EPS)
//   natt[h] = 4 * ||concat(att_l[h], att_r[h])||
//   g[e]    = segment_max(||x||^2, index).flat[index[e]]   (faithful view(-1,1) bug)

static constexpr int   H_        = 4;
static constexpr int   D_        = 32;
static constexpr int   N_NODES   = 50000;
static constexpr float ATT_NORM_ = 4.0f;
static constexpr float EPS_      = 1e-12f;

// Pass A: per-(e,h) squared norm; store norm_x; atomic scatter-max into max_norm.
// Block 0 additionally computes the 4 attention norms (tiny).
__global__ void __launch_bounds__(256)
k_norm_scatter(const float* __restrict__ x,
               const int* __restrict__ index,
               const float* __restrict__ att_l,
               const float* __restrict__ att_r,
               float* __restrict__ max_norm,   // [N*H], pre-zeroed
               float* __restrict__ norm_x,     // [E*H]
               float* __restrict__ natt,       // [H]
               int EH) {
    if (blockIdx.x == 0 && threadIdx.x < H_) {
        const int h = threadIdx.x;
        float s = 0.f;
        #pragma unroll
        for (int d = 0; d < D_; ++d) {
            const float a = att_l[h * D_ + d];
            const float b = att_r[h * D_ + d];
            s += a * a + b * b;
        }
        natt[h] = ATT_NORM_ * sqrtf(s);
    }
    const int p = blockIdx.x * blockDim.x + threadIdx.x;   // pair id = e*H + h
    if (p >= EH) return;

    const float4* xv = reinterpret_cast<const float4*>(x) + (size_t)p * (D_ / 4);
    float s = 0.f;
    #pragma unroll
    for (int j = 0; j < D_ / 4; ++j) {
        const float4 v = xv[j];
        s += v.x * v.x + v.y * v.y + v.z * v.z + v.w * v.w;
    }
    norm_x[p] = s;

    const int e = p >> 2;      // H_ == 4
    const int h = p & 3;
    const int n = index[e];
    // norm >= 0 and table pre-zeroed: int-compare == float-compare for non-negatives.
    atomicMax(reinterpret_cast<int*>(max_norm) + (size_t)n * H_ + h, __float_as_int(s));
}

// Pass B: thread per edge; float4 over the H=4 heads.
__global__ void __launch_bounds__(256)
k_output(const float* __restrict__ alpha,
         const int* __restrict__ index,
         const float* __restrict__ max_norm,   // flat [N*H]
         const float* __restrict__ norm_x,     // [E*H]
         const float* __restrict__ natt,       // [H]
         float* __restrict__ out,              // [E*H]
         int E) {
    const int e = blockIdx.x * blockDim.x + threadIdx.x;
    if (e >= E) return;
    const float n0 = natt[0], n1 = natt[1], n2 = natt[2], n3 = natt[3];
    const float g = max_norm[index[e]];        // faithful flat-gather
    const float4 nx = reinterpret_cast<const float4*>(norm_x)[e];
    const float4 al = reinterpret_cast<const float4*>(alpha)[e];
    float4 o;
    o.x = al.x / (n0 * sqrtf(g + nx.x) + EPS_);
    o.y = al.y / (n1 * sqrtf(g + nx.y) + EPS_);
    o.z = al.z / (n2 * sqrtf(g + nx.z) + EPS_);
    o.w = al.w / (n3 * sqrtf(g + nx.w) + EPS_);
    reinterpret_cast<float4*>(out)[e] = o;
}

// Fallback pass B if ws can't hold norm_x: recompute from x (scalar writes).
__global__ void __launch_bounds__(256)
k_output_recompute(const float* __restrict__ alpha,
                   const int* __restrict__ index,
                   const float* __restrict__ max_norm,
                   const float* __restrict__ x,
                   const float* __restrict__ natt,
                   float* __restrict__ out,
                   int EH) {
    const int p = blockIdx.x * blockDim.x + threadIdx.x;
    if (p >= EH) return;
    const float4* xv = reinterpret_cast<const float4*>(x) + (size_t)p * (D_ / 4);
    float s = 0.f;
    #pragma unroll
    for (int j = 0; j < D_ / 4; ++j) {
        const float4 v = xv[j];
        s += v.x * v.x + v.y * v.y + v.z * v.z + v.w * v.w;
    }
    const int e = p >> 2;
    const int h = p & 3;
    const float g = max_norm[index[e]];
    out[p] = alpha[p] / (natt[h] * sqrtf(g + s) + EPS_);
}

extern "C" void kernel_launch(void* const* d_in, const int* in_sizes, int n_in,
                              void* d_out, int out_size, void* d_ws, size_t ws_size,
                              hipStream_t stream) {
    const float* x     = (const float*)d_in[0];
    const float* att_l = (const float*)d_in[1];
    const float* att_r = (const float*)d_in[2];
    const float* alpha = (const float*)d_in[3];
    const int*   index = (const int*)d_in[4];
    // d_in[5] = num_nodes (device scalar); N fixed at 50000 by the problem.

    const int E  = in_sizes[0] / (H_ * D_);
    const int EH = E * H_;

    char* wsb = (char*)d_ws;
    const size_t maxnorm_bytes = (size_t)N_NODES * H_ * sizeof(float);   // 800 KB
    const size_t normx_bytes   = (size_t)EH * sizeof(float);             // 12.8 MB
    float* max_norm = (float*)wsb;
    float* norm_x   = (float*)(wsb + maxnorm_bytes);
    float* natt     = (float*)(wsb + maxnorm_bytes + normx_bytes);

    const bool have_full_ws = ws_size >= maxnorm_bytes + normx_bytes + H_ * sizeof(float);
    if (!have_full_ws) {
        // minimal layout: max_norm + natt only
        natt   = (float*)(wsb + maxnorm_bytes);
        norm_x = nullptr;
    }

    // zero the scatter-max table every call (harness does not re-poison).
    hipMemsetAsync(max_norm, 0, maxnorm_bytes, stream);

    const int b = 256;
    if (have_full_ws) {
        k_norm_scatter<<<(EH + b - 1) / b, b, 0, stream>>>(
            x, index, att_l, att_r, max_norm, norm_x, natt, EH);
        k_output<<<(E + b - 1) / b, b, 0, stream>>>(
            alpha, index, max_norm, norm_x, natt, (float*)d_out, E);
    } else {
        k_norm_scatter<<<(EH + b - 1) / b, b, 0, stream>>>(
            x, index, att_l, att_r, max_norm, /*norm_x=*/(float*)d_out, natt, EH);
        // d_out used as norm_x scratch above is immediately overwritten below.
        k_output_recompute<<<(EH + b - 1) / b, b, 0, stream>>>(
            alpha, index, max_norm, x, natt, (float*)d_out, EH);
    }
}